// Round 14
// baseline (473.165 us; speedup 1.0000x reference)
//
#include <hip/hip_runtime.h>

#define L 256
#define BATCH 512
#define CIN 32
#define RNNIN 64
#define HIDN 128
#define OUTN 512

typedef _Float16 f16x8 __attribute__((ext_vector_type(8)));
typedef float f32x4 __attribute__((ext_vector_type(4)));
typedef unsigned short u16;

#define MFMA16(a, b, c) __builtin_amdgcn_mfma_f32_16x16x32_f16(a, b, c, 0, 0, 0)

// ws layout: hs @ 0 (33554432 B) fp16 hs[t*65536 + b*128 + j]

// ONE kernel: prep + MFMA RNN (R10 loop VERBATIM -- the 115us local optimum;
// R11-R13 chain restructures all regressed) + per-block pooling + out-GEMM.
// 32 blocks (16 batch rows) x 512 thr (8 waves). Saves 2 launches (~28us each)
// and the pool kernel's cold HBM reread (the block re-reads its own 1MB hs
// slice through L2).
// Prep is spill-free: Wc computed cooperatively (8 scalar accs/thread) into
// LDS -- R13's wihr[64] per-lane array spilled to scratch (FETCH +12MB).
//
// smem map (60KB static):
//   [0,8K)    hbuf [2][16][128] u16     (RNN loop)
//   [8K,40K)  xc [2][16][16][32] u16    (RNN loop)  | WcLds 16K @8K (prep)
//                                       | psred 2K @8K, pooled_s 8K @16K (pool)
//   [40K,60K) winlds 8K + binlds + bprelds (prep) | pstage [128][80] u16 (pool)
__global__ __launch_bounds__(512, 1) void fused_kernel(
    const float* __restrict__ x, const float* __restrict__ h0,
    const float* __restrict__ W_in, const float* __restrict__ b_in,
    const float* __restrict__ W_ih, const float* __restrict__ b_ih,
    const float* __restrict__ W_hh, const float* __restrict__ b_hh,
    const float* __restrict__ W_out, const float* __restrict__ b_out,
    float* __restrict__ out, u16* __restrict__ hs)
{
    __shared__ __align__(16) char smem[61440];
    u16* hbufp = (u16*)smem;                       // (p*16+n)*128 + k
    u16* xcp = (u16*)(smem + 8192);                // ((cb*16+tt)*16+nn)*32 + cc
    float* WcLds = (float*)(smem + 8192);          // 4096 f
    float* psred = (float*)(smem + 8192);          // 512 f (pool)
    float* pooled_s = (float*)(smem + 16384);      // 2048 f (pool)
    float* winlds = (float*)(smem + 40960);        // 2048 f
    float* binlds = (float*)(smem + 49152);        // 64 f
    float* bprelds = (float*)(smem + 49408);       // 128 f
    u16* pstage = (u16*)(smem + 40960);            // 128*80 u16 (pool)

    const int tid = threadIdx.x;
    const int bb = blockIdx.x;
    const int lane = tid & 63;
    const int w = tid >> 6;       // wave 0..7
    const int n = lane & 15;      // batch col / A row
    const int q = lane >> 4;      // quad
    const f32x4 ZERO4 = {0.f, 0.f, 0.f, 0.f};
    const int jr = w * 16 + n;

    // ================= PREP =================
    for (int i = tid; i < RNNIN * CIN; i += 512) winlds[i] = W_in[i];
    if (tid < RNNIN) binlds[tid] = b_in[tid];
    __syncthreads();
    {   // Wc[j][c] = dot64(W_ih[j], W_in[:,c]); thread -> (j=tid>>2, 8 c's)
        const int j = tid >> 2, c0 = (tid & 3) * 8;
        float a8[8];
#pragma unroll
        for (int u = 0; u < 8; ++u) a8[u] = 0.f;
        for (int m = 0; m < RNNIN; ++m) {
            float wv = W_ih[j * RNNIN + m];
#pragma unroll
            for (int u = 0; u < 8; ++u) a8[u] += wv * winlds[m * CIN + c0 + u];
        }
#pragma unroll
        for (int u = 0; u < 8; ++u) WcLds[j * CIN + c0 + u] = a8[u];
    }
    if (tid < HIDN) {
        float bs = b_ih[tid] + b_hh[tid];
        for (int m = 0; m < RNNIN; ++m) bs += W_ih[tid * RNNIN + m] * binlds[m];
        bprelds[tid] = bs;
    }
    __syncthreads();

    // A-frags: fp32 W_hh -> fp16 hi/lo split in regs; Axh/Axl from WcLds
    f16x8 Ah[4], Al[4], Axh, Axl;
#pragma unroll
    for (int kc = 0; kc < 4; ++kc) {
        const float* src = W_hh + jr * HIDN + kc * 32 + q * 8;
        float4 va = *(const float4*)(src);
        float4 vb = *(const float4*)(src + 4);
        float vv[8] = {va.x, va.y, va.z, va.w, vb.x, vb.y, vb.z, vb.w};
#pragma unroll
        for (int i = 0; i < 8; ++i) {
            _Float16 h = (_Float16)vv[i];
            Ah[kc][i] = h;
            Al[kc][i] = (_Float16)(vv[i] - (float)h);
        }
    }
#pragma unroll
    for (int i = 0; i < 8; ++i) {
        float v = WcLds[jr * CIN + q * 8 + i];
        _Float16 h = (_Float16)v;
        Axh[i] = h;
        Axl[i] = (_Float16)(v - (float)h);
    }
    float4 bv = *(const float4*)(bprelds + w * 16 + q * 4);
    f32x4 bp = {bv.x, bv.y, bv.z, bv.w};

    // h0 -> fp16 plane, dbuf 0
    if (tid < 256) {
        const int ni = tid >> 4, gi = tid & 15;
        const float4* src = (const float4*)(h0 + ((size_t)bb * 16 + ni) * HIDN + gi * 8);
        float4 a = src[0], b4 = src[1];
        float vv[8] = {a.x, a.y, a.z, a.w, b4.x, b4.y, b4.z, b4.w};
        u16 o[8];
#pragma unroll
        for (int i = 0; i < 8; ++i) {
            _Float16 h = (_Float16)vv[i];
            __builtin_memcpy(&o[i], &h, 2);
        }
        *(uint4*)&hbufp[(0 * 16 + ni) * HIDN + (gi ^ (ni & 7)) * 8] = *(uint4*)o;
    }
    __syncthreads();   // all WcLds reads done before xc (same region) is written

    // x chunk staging (R10): i=tid+r*512 -> (nn,cc,tq)
    float4 xr[4];
    auto issue_chunk = [&](int ci) {
#pragma unroll
        for (int r = 0; r < 4; ++r) {
            int i = tid + r * 512;
            int nn = i >> 7, cc = (i >> 2) & 31, tq = i & 3;
            xr[r] = *(const float4*)(x + (((size_t)bb * 16 + nn) * CIN + cc) * L + ci * 16 + tq * 4);
        }
    };
    auto write_chunk = [&](int buf) {
#pragma unroll
        for (int r = 0; r < 4; ++r) {
            int i = tid + r * 512;
            int nn = i >> 7, cc = (i >> 2) & 31, tq = i & 3;
            float vv[4] = {xr[r].x, xr[r].y, xr[r].z, xr[r].w};
#pragma unroll
            for (int k = 0; k < 4; ++k) {
                _Float16 h = (_Float16)vv[k];
                u16 u; __builtin_memcpy(&u, &h, 2);
                xcp[((buf * 16 + tq * 4 + k) * 16 + nn) * 32 + cc] = u;
            }
        }
    };

    issue_chunk(0);
    write_chunk(0);
    issue_chunk(1);
    __syncthreads();

    u16* hsp = hs + ((size_t)bb * 16 + n) * HIDN + w * 16 + q * 4;

    // ================= RNN LOOP (R10 verbatim) =================
    for (int t = 0; t < L; ++t) {
        const int p = t & 1;
        const int cb = (t >> 4) & 1, tt = t & 15;

        f16x8 Bh[4];
#pragma unroll
        for (int kc = 0; kc < 4; ++kc)
            Bh[kc] = *(const f16x8*)&hbufp[(p * 16 + n) * HIDN + ((4 * kc + q) ^ (n & 7)) * 8];
        f16x8 xB = *(const f16x8*)&xcp[((cb * 16 + tt) * 16 + n) * 32 + q * 8];

        f32x4 aH = bp;
        f32x4 aL = ZERO4;
#pragma unroll
        for (int kc = 0; kc < 4; ++kc) {
            aH = MFMA16(Ah[kc], Bh[kc], aH);
            aL = MFMA16(Al[kc], Bh[kc], aL);
        }
        aH = MFMA16(Axh, xB, aH);
        aL = MFMA16(Axl, xB, aL);

        if (tt == 15 && t < L - 16) {
            write_chunk(cb ^ 1);
            if (t < L - 32) issue_chunk((t >> 4) + 2);
        }

        f32x4 acc = aH + aL;
        u16 o[4];
#pragma unroll
        for (int r = 0; r < 4; ++r) {
            float e = __expf(2.f * acc[r]);
            float hv = 1.f - 2.f * __builtin_amdgcn_rcpf(e + 1.f);
            _Float16 h = (_Float16)hv;
            __builtin_memcpy(&o[r], &h, 2);
        }
        uint2 pk; __builtin_memcpy(&pk, o, 8);
        const int G = (w * 2 + (q >> 1)) ^ (n & 7);
        *(uint2*)&hbufp[((p ^ 1) * 16 + n) * HIDN + G * 8 + (q & 1) * 4] = pk;
        *(uint2*)(hsp + (size_t)t * (BATCH * HIDN)) = pk;

        asm volatile("" ::: "memory");
        __builtin_amdgcn_s_waitcnt(0xC07F);   // lgkmcnt(0) only; stores in flight
        __builtin_amdgcn_s_barrier();
        asm volatile("" ::: "memory");
    }

    // ================= POOL (own 16 rows via L2) =================
    __builtin_amdgcn_s_waitcnt(0);   // drain hs stores before reread
    __syncthreads();

    const int jj = tid & 127;
    const int grp = tid >> 7;        // 0..3
    const int ybase[4] = {0, 4, 8, 12};
    const int rcnt[4]  = {5, 5, 5, 4};
    const int oys[4]   = {0, 9, 17, 25};
    const int oye[4]   = {8, 16, 24, 31};

    for (int nn2 = 0; nn2 < 16; ++nn2) {
        float pacc = 0.f;
        for (int qq = 0; qq < 4; ++qq) {
            __syncthreads();   // prev eval done before pstage overwrite
            const int yb = ybase[qq], R = rcnt[qq];
            for (int i = tid; i < R * 16 * 16; i += 512) {
                int tr = i >> 4, g = i & 15;
                uint4 v = *(const uint4*)(hs + (size_t)(16 * yb + tr) * (BATCH * HIDN)
                                          + ((size_t)bb * 16 + nn2) * HIDN + g * 8);
                u16 tmp[8]; __builtin_memcpy(tmp, &v, 16);
#pragma unroll
                for (int u = 0; u < 8; ++u) pstage[(g * 8 + u) * 80 + tr] = tmp[u];
            }
            __syncthreads();
            for (int oy = oys[qq] + grp; oy <= oye[qq]; oy += 4) {
                float ysf = oy * (15.f / 31.f);
                int y0 = (int)ysf; float wy = ysf - (float)y0;
                int y1 = min(y0 + 1, 15);
                int r0 = y0 - yb, r1 = y1 - yb;
                f16x8 p00 = *(const f16x8*)(pstage + jj * 80 + r0 * 16);
                f16x8 p01 = *(const f16x8*)(pstage + jj * 80 + r0 * 16 + 8);
                f16x8 p10 = *(const f16x8*)(pstage + jj * 80 + r1 * 16);
                f16x8 p11 = *(const f16x8*)(pstage + jj * 80 + r1 * 16 + 8);
                float rbv[16];
#pragma unroll
                for (int u = 0; u < 8; ++u) {
                    float a0 = (float)p00[u], a1 = (float)p10[u];
                    rbv[u] = a0 + wy * (a1 - a0);
                    float b0 = (float)p01[u], b1 = (float)p11[u];
                    rbv[8 + u] = b0 + wy * (b1 - b0);
                }
#pragma unroll
                for (int ox = 0; ox < 32; ++ox) {
                    float xsf = ox * (15.f / 31.f);
                    int x0 = (int)xsf; float wx = xsf - (float)x0;
                    int x1 = (x0 + 1 > 15) ? 15 : x0 + 1;
                    float v = rbv[x0] + wx * (rbv[x1] - rbv[x0]);
                    float t6 = fminf(fmaxf(v + 3.f, 0.f), 6.f);
                    pacc += v * t6;
                }
            }
        }
        psred[grp * 128 + jj] = pacc;
        __syncthreads();
        if (grp == 0)
            pooled_s[nn2 * 128 + jj] =
                (psred[jj] + psred[128 + jj] + psred[256 + jj] + psred[384 + jj]) * (1.f / 6144.f);
    }
    __syncthreads();

    // ================= OUT-GEMM =================
    {
        const int o = tid;   // 512 outputs, 1 per thread; 16 batch accs
        float oacc[16];
        float bo = b_out[o];
#pragma unroll
        for (int i2 = 0; i2 < 16; ++i2) oacc[i2] = bo;
        for (int k = 0; k < HIDN; k += 4) {
            float4 wv = *(const float4*)(W_out + o * HIDN + k);
#pragma unroll
            for (int i2 = 0; i2 < 16; ++i2) {
                float4 pv = *(const float4*)(pooled_s + i2 * 128 + k);  // broadcast
                oacc[i2] += wv.x * pv.x + wv.y * pv.y + wv.z * pv.z + wv.w * pv.w;
            }
        }
#pragma unroll
        for (int i2 = 0; i2 < 16; ++i2)
            out[((size_t)bb * 16 + i2) * OUTN + o] = oacc[i2];
    }
}

extern "C" void kernel_launch(void* const* d_in, const int* in_sizes, int n_in,
                              void* d_out, int out_size, void* d_ws, size_t ws_size,
                              hipStream_t stream)
{
    const float* x     = (const float*)d_in[0];
    const float* h0    = (const float*)d_in[1];
    const float* W_in  = (const float*)d_in[2];
    const float* b_in  = (const float*)d_in[3];
    const float* W_ih  = (const float*)d_in[4];
    const float* b_ih  = (const float*)d_in[5];
    const float* W_hh  = (const float*)d_in[6];
    const float* b_hh  = (const float*)d_in[7];
    const float* W_out = (const float*)d_in[8];
    const float* b_out = (const float*)d_in[9];
    float* out = (float*)d_out;
    u16* hsb = (u16*)d_ws;

    fused_kernel<<<32, 512, 0, stream>>>(x, h0, W_in, b_in, W_ih, b_ih,
                                         W_hh, b_hh, W_out, b_out, out, hsb);
}